// Round 2
// baseline (508.727 us; speedup 1.0000x reference)
//
#include <hip/hip_runtime.h>
#include <stdint.h>

#define B_  32
#define CIN 64
#define H_  56
#define W_  56
#define HW_ 3136
#define P_  384
#define CO_ 96

typedef unsigned char u8;

// exp2(ceil(log2(max(m,1e-8)/n))) computed exactly (handles pot boundary via frexp)
__device__ __forceinline__ float pot_scale(float m, float n) {
    float q = fmaxf(m, 1e-8f) / n;
    int e; float f = frexpf(q, &e);        // q = f*2^e, f in [0.5,1)
    return ldexpf(1.0f, (f == 0.5f) ? (e - 1) : e);
}

__device__ __forceinline__ int dot4(int a, int b, int c) {
#if __has_builtin(__builtin_amdgcn_sdot4)
    return __builtin_amdgcn_sdot4(a, b, c, false);
#else
    c += (int)(int8_t)(a & 0xff)         * (int)(int8_t)(b & 0xff);
    c += (int)(int8_t)((a >> 8) & 0xff)  * (int)(int8_t)((b >> 8) & 0xff);
    c += (int)(int8_t)((a >> 16) & 0xff) * (int)(int8_t)((b >> 16) & 0xff);
    c += (int)(int8_t)(a >> 24)          * (int)(int8_t)(b >> 24);
    return c;
#endif
}

__device__ __forceinline__ int pack4(int q0, int q1, int q2, int q3) {
    return (q0 & 0xff) | ((q1 & 0xff) << 8) | ((q2 & 0xff) << 16) |
           (int)((unsigned)(q3 & 0xff) << 24);
}

__device__ __forceinline__ int iclamp(int v, int lo, int hi) { return min(max(v, lo), hi); }

__device__ __forceinline__ int block_max(int v, int* red) {
    int tid = threadIdx.x;
    red[tid] = v; __syncthreads();
    for (int s = 128; s > 0; s >>= 1) {
        if (tid < s) red[tid] = max(red[tid], red[tid + s]);
        __syncthreads();
    }
    int r = red[0];
    __syncthreads();
    return r;
}

// scalar slots (int/float view of same 128B): sf[0]=max|x|, sf[1..4]=max|w1,w2,w3,ws|
// si[5]=maxL1, si[6]=maxL2, si[7]=maxAcc3, si[8]=maxAccS
// bnb: inv1[0:384] beta1[384:768] inv2[768:1152] beta2[1152:1536]
//      inv3[1536:1632] beta3[1632:1728] invs[1728:1824] betas[1824:1920]

__global__ __launch_bounds__(1024) void k_init_bn(
    float* sf, float* bnb,
    const float* g1, const float* b1, const float* m1, const float* v1,
    const float* g2, const float* b2, const float* m2, const float* v2,
    const float* g3, const float* b3, const float* m3, const float* v3,
    const float* gs, const float* bs, const float* ms, const float* vs)
{
    int t = threadIdx.x;
    if (t < 32) ((int*)sf)[t] = 0;
    if (t < 384) {
        float inv = __fmul_rn(g1[t], __fdiv_rn(1.0f, sqrtf(__fadd_rn(v1[t], 1e-5f))));
        bnb[t] = inv;
        bnb[384 + t] = __fsub_rn(b1[t], __fmul_rn(m1[t], inv));
    } else if (t < 768) {
        int i = t - 384;
        float inv = __fmul_rn(g2[i], __fdiv_rn(1.0f, sqrtf(__fadd_rn(v2[i], 1e-5f))));
        bnb[768 + i] = inv;
        bnb[1152 + i] = __fsub_rn(b2[i], __fmul_rn(m2[i], inv));
    } else if (t < 864) {
        int i = t - 768;
        float inv = __fmul_rn(g3[i], __fdiv_rn(1.0f, sqrtf(__fadd_rn(v3[i], 1e-5f))));
        bnb[1536 + i] = inv;
        bnb[1632 + i] = __fsub_rn(b3[i], __fmul_rn(m3[i], inv));
    } else if (t < 960) {
        int i = t - 864;
        float inv = __fmul_rn(gs[i], __fdiv_rn(1.0f, sqrtf(__fadd_rn(vs[i], 1e-5f))));
        bnb[1728 + i] = inv;
        bnb[1824 + i] = __fsub_rn(bs[i], __fmul_rn(ms[i], inv));
    }
}

__global__ __launch_bounds__(256) void k_maxes(
    const float* __restrict__ x, const float* __restrict__ w1,
    const float* __restrict__ w2, const float* __restrict__ w3,
    const float* __restrict__ wsc, float* sf)
{
    __shared__ int red[256];
    int tid = threadIdx.x;
    float m = 0.f;
    if (blockIdx.x < 512) {
        const float4* x4 = (const float4*)x;
        const int n4 = (B_ * CIN * HW_) / 4;   // 1605632
        for (int i = blockIdx.x * 256 + tid; i < n4; i += 512 * 256) {
            float4 v = x4[i];
            m = fmaxf(m, fmaxf(fmaxf(fabsf(v.x), fabsf(v.y)),
                               fmaxf(fabsf(v.z), fabsf(v.w))));
        }
        int bm = block_max(__float_as_int(m), red);
        if (tid == 0) atomicMax((int*)&sf[0], bm);
    } else {
        int seg = blockIdx.x - 512;
        const float* p = seg == 0 ? w1 : seg == 1 ? w2 : seg == 2 ? w3 : wsc;
        int n = seg == 0 ? P_ * CIN : seg == 1 ? P_ * 9 : seg == 2 ? CO_ * P_ : CO_ * CIN;
        for (int i = tid; i < n; i += 256) m = fmaxf(m, fabsf(p[i]));
        int bm = block_max(__float_as_int(m), red);
        if (tid == 0) atomicMax((int*)&sf[1 + seg], bm);
    }
}

__global__ __launch_bounds__(256) void k_quantx(
    const float* __restrict__ x, const float* __restrict__ sf, int* __restrict__ xqp)
{
    int flat = blockIdx.x * 256 + threadIdx.x;     // 6272*256 == 1605632 exact
    const int N = B_ * 16 * HW_;
    if (flat >= N) return;
    float rx = 1.0f / pot_scale(sf[0], 7.0f);      // exact pot
    int hw = flat % HW_;
    int c4 = (flat / HW_) & 15;
    int b  = flat / (16 * HW_);
    const float* xp = x + (size_t)(b * 64 + c4 * 4) * HW_ + hw;
    int q[4];
#pragma unroll
    for (int j = 0; j < 4; j++)
        q[j] = iclamp((int)rintf(__fmul_rn(xp[(size_t)j * HW_], rx)), -8, 7);
    xqp[flat] = pack4(q[0], q[1], q[2], q[3]);
}

__global__ __launch_bounds__(256) void k_quantw(
    const float* __restrict__ w1, const float* __restrict__ w2,
    const float* __restrict__ w3, const float* __restrict__ wsc,
    const float* __restrict__ sf,
    int* __restrict__ w1q, int8_t* __restrict__ w2q,
    int* __restrict__ w3q, int* __restrict__ wsq)
{
    int flat = blockIdx.x * 256 + threadIdx.x;
    if (flat < 6144) {                               // w1: [384][64] -> [384][16] packed
        float r = 1.0f / pot_scale(sf[1], 7.f);
        int p = flat >> 4, c4 = flat & 15;
        const float* src = w1 + p * 64 + c4 * 4;
        int q[4];
#pragma unroll
        for (int j = 0; j < 4; j++)
            q[j] = iclamp((int)rintf(__fmul_rn(src[j], r)), -8, 7);
        w1q[flat] = pack4(q[0], q[1], q[2], q[3]);
    } else if (flat < 15360) {                       // w3: [96][384] -> [96][96] packed
        int i = flat - 6144;
        float r = 1.0f / pot_scale(sf[3], 7.f);
        int co = i / 96, c4 = i % 96;
        const float* src = w3 + co * 384 + c4 * 4;
        int q[4];
#pragma unroll
        for (int j = 0; j < 4; j++)
            q[j] = iclamp((int)rintf(__fmul_rn(src[j], r)), -8, 7);
        w3q[i] = pack4(q[0], q[1], q[2], q[3]);
    } else if (flat < 16896) {                       // ws: [96][64] -> [96][16] packed
        int i = flat - 15360;
        float r = 1.0f / pot_scale(sf[4], 7.f);
        int co = i >> 4, c4 = i & 15;
        const float* src = wsc + co * 64 + c4 * 4;
        int q[4];
#pragma unroll
        for (int j = 0; j < 4; j++)
            q[j] = iclamp((int)rintf(__fmul_rn(src[j], r)), -8, 7);
        wsq[i] = pack4(q[0], q[1], q[2], q[3]);
    } else if (flat < 20352) {                       // w2: [384*9] int8
        int i = flat - 16896;
        float r = 1.0f / pot_scale(sf[2], 7.f);
        w2q[i] = (int8_t)iclamp((int)rintf(__fmul_rn(w2[i], r)), -8, 7);
    }
}

// expand 1x1 (64->384) + BN1 + QuantReLU4 -> uint8 levels; track max level
__global__ __launch_bounds__(256) void k_conv1(
    const int* __restrict__ xqp, const int* __restrict__ w1q,
    const float* __restrict__ sf, const float* __restrict__ bnb,
    u8* __restrict__ out1, int* si)
{
    __shared__ int w1s[P_ * 16];
    __shared__ int xs[16 * W_];
    __shared__ int red[256];
    int tid = threadIdx.x;
    int b = blockIdx.x / H_, h = blockIdx.x % H_;
    for (int i = tid; i < P_ * 16; i += 256) w1s[i] = w1q[i];
    for (int i = tid; i < 16 * W_; i += 256)
        xs[i] = xqp[((b * 16 + i / W_) * HW_) + h * W_ + (i % W_)];
    float sprod = __fmul_rn(pot_scale(sf[0], 7.f), pot_scale(sf[1], 7.f)); // exact pot
    __syncthreads();
    int lmax = 0;
    for (int qi = tid; qi < P_ * 14; qi += 256) {    // 5376 quads, 21 iters
        int p = qi / 14, w4 = (qi % 14) * 4;
        int a0 = 0, a1 = 0, a2 = 0, a3 = 0;
        const int* wp = w1s + p * 16;
        const int* xp = xs + w4;
#pragma unroll
        for (int k = 0; k < 16; k++) {
            int wv = wp[k];
            int4 av = *(const int4*)(xp + k * W_);
            a0 = dot4(av.x, wv, a0); a1 = dot4(av.y, wv, a1);
            a2 = dot4(av.z, wv, a2); a3 = dot4(av.w, wv, a3);
        }
        float inv = bnb[p], beta = bnb[P_ + p];
        int acc[4] = {a0, a1, a2, a3};
        unsigned pkd = 0;
#pragma unroll
        for (int j = 0; j < 4; j++) {
            float y = __fadd_rn(__fmul_rn(__fmul_rn((float)acc[j], sprod), inv), beta);
            int L = iclamp((int)rintf(__fmul_rn(y, 4.f)), 0, 15);
            lmax = max(lmax, L);
            pkd |= (unsigned)L << (8 * j);
        }
        *(unsigned*)(out1 + ((size_t)(b * P_ + p) * HW_ + h * W_ + w4)) = pkd;
    }
    int bm = block_max(lmax, red);
    if (tid == 0) atomicMax(&si[5], bm);
}

// depthwise 3x3 + BN2 + QuantReLU4 -> uint8 levels; track max level
__global__ __launch_bounds__(256) void k_conv2(
    const u8* __restrict__ out1, const int8_t* __restrict__ w2q,
    const float* __restrict__ sf, int* si,
    const float* __restrict__ bnb, u8* __restrict__ out2)
{
    __shared__ int8_t plane[58 * 58];
    __shared__ int red[256];
    int tid = threadIdx.x;
    int b = blockIdx.x / P_, p = blockIdx.x % P_;
    float s_a2 = pot_scale(0.25f * (float)si[5], 7.f);
    float r2 = 0.25f / s_a2;                         // exact pot ratio
    float sprod = __fmul_rn(s_a2, pot_scale(sf[2], 7.f));
    const u8* src = out1 + (size_t)(b * P_ + p) * HW_;
    for (int i = tid; i < 58 * 58; i += 256) {
        int r = i / 58, c = i % 58;
        int v = 0;
        if (r >= 1 && r <= 56 && c >= 1 && c <= 56)
            v = min((int)rintf(__fmul_rn((float)src[(r - 1) * W_ + (c - 1)], r2)), 7);
        plane[i] = (int8_t)v;
    }
    int wv[9];
#pragma unroll
    for (int j = 0; j < 9; j++) wv[j] = w2q[p * 9 + j];
    float inv = bnb[768 + p], beta = bnb[1152 + p];
    __syncthreads();
    int lmax = 0;
    u8* dst = out2 + (size_t)(b * P_ + p) * HW_;
    for (int i = tid; i < HW_; i += 256) {
        int oh = i / W_, ow = i % W_;
        const int8_t* pp = plane + oh * 58 + ow;
        int acc = pp[0] * wv[0] + pp[1] * wv[1] + pp[2] * wv[2]
                + pp[58] * wv[3] + pp[59] * wv[4] + pp[60] * wv[5]
                + pp[116] * wv[6] + pp[117] * wv[7] + pp[118] * wv[8];
        float y = __fadd_rn(__fmul_rn(__fmul_rn((float)acc, sprod), inv), beta);
        int L = iclamp((int)rintf(__fmul_rn(y, 4.f)), 0, 15);
        lmax = max(lmax, L);
        dst[i] = (u8)L;
    }
    int bm = block_max(lmax, red);
    if (tid == 0) atomicMax(&si[6], bm);
}

// project 1x1 (384->96): integer accumulators -> int16, track max|acc|
__global__ __launch_bounds__(256) void k_conv3(
    const u8* __restrict__ out2, const int* __restrict__ w3q,
    const float* __restrict__ sf, int* si,
    int16_t* __restrict__ acc3)
{
    __shared__ int w3s[CO_ * 96];
    __shared__ int a3s[96 * W_];
    __shared__ int red[256];
    int tid = threadIdx.x;
    int b = blockIdx.x / H_, h = blockIdx.x % H_;
    float s_a3 = pot_scale(0.25f * (float)si[6], 7.f);
    float r3 = 0.25f / s_a3;
    for (int i = tid; i < CO_ * 96; i += 256) w3s[i] = w3q[i];
    for (int i = tid; i < 96 * W_; i += 256) {
        int c4 = i / W_, w = i % W_;
        const u8* src = out2 + ((size_t)(b * P_ + c4 * 4) * HW_) + h * W_ + w;
        int q0 = min((int)rintf(__fmul_rn((float)src[0], r3)), 7);
        int q1 = min((int)rintf(__fmul_rn((float)src[HW_], r3)), 7);
        int q2 = min((int)rintf(__fmul_rn((float)src[2 * HW_], r3)), 7);
        int q3 = min((int)rintf(__fmul_rn((float)src[3 * HW_], r3)), 7);
        a3s[i] = pack4(q0, q1, q2, q3);
    }
    __syncthreads();
    int amax = 0;
    for (int qi = tid; qi < CO_ * 14; qi += 256) {   // 1344 quads
        int co = qi / 14, w4 = (qi % 14) * 4;
        int a0 = 0, a1 = 0, a2 = 0, a3v = 0;
        const int* wp = w3s + co * 96;
        const int* ap = a3s + w4;
#pragma unroll 8
        for (int k = 0; k < 96; k++) {
            int wv = wp[k];
            int4 av = *(const int4*)(ap + k * W_);
            a0 = dot4(av.x, wv, a0); a1 = dot4(av.y, wv, a1);
            a2 = dot4(av.z, wv, a2); a3v = dot4(av.w, wv, a3v);
        }
        amax = max(amax, max(max(abs(a0), abs(a1)), max(abs(a2), abs(a3v))));
        short4 st = make_short4((short)a0, (short)a1, (short)a2, (short)a3v);
        *(short4*)(acc3 + (size_t)(b * CO_ + co) * HW_ + h * W_ + w4) = st;
    }
    int bm = block_max(amax, red);
    if (tid == 0) atomicMax(&si[7], bm);
}

// shortcut 1x1 (64->96): only need max|acc| (values recomputed in k_final)
__global__ __launch_bounds__(256) void k_convs(
    const int* __restrict__ xqp, const int* __restrict__ wsq, int* si)
{
    __shared__ int wss[CO_ * 16];
    __shared__ int xs[16 * W_];
    __shared__ int red[256];
    int tid = threadIdx.x;
    int b = blockIdx.x / H_, h = blockIdx.x % H_;
    for (int i = tid; i < CO_ * 16; i += 256) wss[i] = wsq[i];
    for (int i = tid; i < 16 * W_; i += 256)
        xs[i] = xqp[((b * 16 + i / W_) * HW_) + h * W_ + (i % W_)];
    __syncthreads();
    int amax = 0;
    for (int qi = tid; qi < CO_ * 14; qi += 256) {
        int co = qi / 14, w4 = (qi % 14) * 4;
        int a0 = 0, a1 = 0, a2 = 0, a3 = 0;
        const int* wp = wss + co * 16;
        const int* xp = xs + w4;
#pragma unroll
        for (int k = 0; k < 16; k++) {
            int wv = wp[k];
            int4 av = *(const int4*)(xp + k * W_);
            a0 = dot4(av.x, wv, a0); a1 = dot4(av.y, wv, a1);
            a2 = dot4(av.z, wv, a2); a3 = dot4(av.w, wv, a3);
        }
        amax = max(amax, max(max(abs(a0), abs(a1)), max(abs(a2), abs(a3))));
    }
    int bm = block_max(amax, red);
    if (tid == 0) atomicMax(&si[8], bm);
}

// fq8(conv3)+BN3 + fq4(shortcut)+BNs + add + QuantReLU4 -> fp32 out
__global__ __launch_bounds__(256) void k_final(
    const int* __restrict__ xqp, const int* __restrict__ wsq,
    const int16_t* __restrict__ acc3, const float* __restrict__ sf,
    const int* __restrict__ si, const float* __restrict__ bnb,
    float* __restrict__ dout)
{
    __shared__ int wss[CO_ * 16];
    __shared__ int xs[16 * W_];
    int tid = threadIdx.x;
    int b = blockIdx.x / H_, h = blockIdx.x % H_;
    for (int i = tid; i < CO_ * 16; i += 256) wss[i] = wsq[i];
    for (int i = tid; i < 16 * W_; i += 256)
        xs[i] = xqp[((b * 16 + i / W_) * HW_) + h * W_ + (i % W_)];
    float s_a3   = pot_scale(0.25f * (float)si[6], 7.f);
    float sprod3 = __fmul_rn(s_a3, pot_scale(sf[3], 7.f));
    float s_q3   = pot_scale(__fmul_rn(sprod3, (float)si[7]), 127.f);
    float rq3    = sprod3 / s_q3;                    // exact pot ratio
    float sprods = __fmul_rn(pot_scale(sf[0], 7.f), pot_scale(sf[4], 7.f));
    float s_qs   = pot_scale(__fmul_rn(sprods, (float)si[8]), 7.f);
    float rqs    = sprods / s_qs;
    __syncthreads();
    for (int qi = tid; qi < CO_ * 14; qi += 256) {
        int co = qi / 14, w4 = (qi % 14) * 4;
        int a0 = 0, a1 = 0, a2 = 0, a3v = 0;
        const int* wp = wss + co * 16;
        const int* xp = xs + w4;
#pragma unroll
        for (int k = 0; k < 16; k++) {
            int wv = wp[k];
            int4 av = *(const int4*)(xp + k * W_);
            a0 = dot4(av.x, wv, a0); a1 = dot4(av.y, wv, a1);
            a2 = dot4(av.z, wv, a2); a3v = dot4(av.w, wv, a3v);
        }
        size_t idx = (size_t)(b * CO_ + co) * HW_ + h * W_ + w4;
        short4 c3 = *(const short4*)(acc3 + idx);
        float inv3 = bnb[1536 + co], beta3 = bnb[1632 + co];
        float invS = bnb[1728 + co], betaS = bnb[1824 + co];
        int accs[4] = {a0, a1, a2, a3v};
        int c3a[4] = {c3.x, c3.y, c3.z, c3.w};
        float4 o4;
        float* o = (float*)&o4;
#pragma unroll
        for (int j = 0; j < 4; j++) {
            int q3 = iclamp((int)rintf(__fmul_rn((float)c3a[j], rq3)), -128, 127);
            float y3 = __fadd_rn(__fmul_rn(__fmul_rn((float)q3, s_q3), inv3), beta3);
            int qs = iclamp((int)rintf(__fmul_rn((float)accs[j], rqs)), -8, 7);
            float ys = __fadd_rn(__fmul_rn(__fmul_rn((float)qs, s_qs), invS), betaS);
            float oo = __fadd_rn(y3, ys);
            int L = iclamp((int)rintf(__fmul_rn(oo, 4.f)), 0, 15);
            o[j] = (float)L * 0.25f;
        }
        *(float4*)(dout + idx) = o4;
    }
}

extern "C" void kernel_launch(void* const* d_in, const int* in_sizes, int n_in,
                              void* d_out, int out_size, void* d_ws, size_t ws_size,
                              hipStream_t stream)
{
    const float* x   = (const float*)d_in[0];
    const float* w1  = (const float*)d_in[1];
    const float* g1  = (const float*)d_in[2];
    const float* b1  = (const float*)d_in[3];
    const float* m1  = (const float*)d_in[4];
    const float* v1  = (const float*)d_in[5];
    const float* w2  = (const float*)d_in[6];
    const float* g2  = (const float*)d_in[7];
    const float* b2  = (const float*)d_in[8];
    const float* m2  = (const float*)d_in[9];
    const float* v2  = (const float*)d_in[10];
    const float* w3  = (const float*)d_in[11];
    const float* g3  = (const float*)d_in[12];
    const float* b3  = (const float*)d_in[13];
    const float* m3  = (const float*)d_in[14];
    const float* v3  = (const float*)d_in[15];
    const float* wsc = (const float*)d_in[16];
    const float* gs  = (const float*)d_in[17];
    const float* bs  = (const float*)d_in[18];
    const float* ms  = (const float*)d_in[19];
    const float* vs  = (const float*)d_in[20];

    char* ws = (char*)d_ws;
    float*   sf   = (float*)ws;
    int*     si   = (int*)ws;
    float*   bnb  = (float*)(ws + 256);
    int*     w1q  = (int*)(ws + 8192);
    int8_t*  w2q  = (int8_t*)(ws + 32768);
    int*     w3q  = (int*)(ws + 36864);
    int*     wsq  = (int*)(ws + 73728);
    int*     xqp  = (int*)(ws + (1u << 20));
    u8*      out1 = (u8*)(ws + (8u << 20));
    int16_t* acc3 = (int16_t*)(ws + (8u << 20));   // aliases out1 (dead after conv2)
    u8*      out2 = (u8*)(ws + (48u << 20));

    k_init_bn<<<1, 1024, 0, stream>>>(sf, bnb, g1, b1, m1, v1, g2, b2, m2, v2,
                                      g3, b3, m3, v3, gs, bs, ms, vs);
    k_maxes<<<516, 256, 0, stream>>>(x, w1, w2, w3, wsc, sf);
    k_quantx<<<6272, 256, 0, stream>>>(x, sf, xqp);
    k_quantw<<<80, 256, 0, stream>>>(w1, w2, w3, wsc, sf, w1q, w2q, w3q, wsq);
    k_conv1<<<B_ * H_, 256, 0, stream>>>(xqp, w1q, sf, bnb, out1, si);
    k_conv2<<<B_ * P_, 256, 0, stream>>>(out1, w2q, sf, si, bnb, out2);
    k_conv3<<<B_ * H_, 256, 0, stream>>>(out2, w3q, sf, si, acc3);
    k_convs<<<B_ * H_, 256, 0, stream>>>(xqp, wsq, si);
    k_final<<<B_ * H_, 256, 0, stream>>>(xqp, wsq, acc3, sf, si, bnb, (float*)d_out);
}

// Round 3
// 340.212 us; speedup vs baseline: 1.4953x; 1.4953x over previous
//
#include <hip/hip_runtime.h>
#include <stdint.h>

#define B_  32
#define CIN 64
#define H_  56
#define W_  56
#define HW_ 3136
#define P_  384
#define CO_ 96

typedef unsigned char u8;

// exp2(ceil(log2(max(m,1e-8)/n))) computed exactly (handles pot boundary via frexp)
__device__ __forceinline__ float pot_scale(float m, float n) {
    float q = fmaxf(m, 1e-8f) / n;
    int e; float f = frexpf(q, &e);        // q = f*2^e, f in [0.5,1)
    return ldexpf(1.0f, (f == 0.5f) ? (e - 1) : e);
}

__device__ __forceinline__ int dot4(int a, int b, int c) {
#if __has_builtin(__builtin_amdgcn_sdot4)
    return __builtin_amdgcn_sdot4(a, b, c, false);
#else
    c += (int)(int8_t)(a & 0xff)         * (int)(int8_t)(b & 0xff);
    c += (int)(int8_t)((a >> 8) & 0xff)  * (int)(int8_t)((b >> 8) & 0xff);
    c += (int)(int8_t)((a >> 16) & 0xff) * (int)(int8_t)((b >> 16) & 0xff);
    c += (int)(int8_t)(a >> 24)          * (int)(int8_t)(b >> 24);
    return c;
#endif
}

__device__ __forceinline__ int pack4(int q0, int q1, int q2, int q3) {
    return (q0 & 0xff) | ((q1 & 0xff) << 8) | ((q2 & 0xff) << 16) |
           (int)((unsigned)(q3 & 0xff) << 24);
}

__device__ __forceinline__ int iclamp(int v, int lo, int hi) { return min(max(v, lo), hi); }

// 16-entry level->level LUT (q = min(rint(L*r),7)) packed into two regs, 4b/entry.
// Bit-identical to computing rintf(__fmul_rn((float)L, r)) per element.
__device__ __forceinline__ unsigned build_lut(float r, int lo) {
    unsigned v = 0;
#pragma unroll
    for (int L = 0; L < 8; L++)
        v |= (unsigned)min((int)rintf(__fmul_rn((float)(lo + L), r)), 7) << (4 * L);
    return v;
}
__device__ __forceinline__ int lut1(unsigned lo, unsigned hi, int L) {
    unsigned sel = (L & 8) ? hi : lo;
    return (int)((sel >> ((L & 7) * 4)) & 7u);
}
__device__ __forceinline__ int lutq4(unsigned lo, unsigned hi, unsigned v) {
    return lut1(lo, hi, (int)(v & 0xffu))
         | (lut1(lo, hi, (int)((v >> 8) & 0xffu)) << 8)
         | (lut1(lo, hi, (int)((v >> 16) & 0xffu)) << 16)
         | (lut1(lo, hi, (int)((v >> 24) & 0xffu)) << 24);
}

__device__ __forceinline__ int block_max(int v, int* red) {
    int tid = threadIdx.x;
    red[tid] = v; __syncthreads();
    for (int s = 128; s > 0; s >>= 1) {
        if (tid < s) red[tid] = max(red[tid], red[tid + s]);
        __syncthreads();
    }
    int r = red[0];
    __syncthreads();
    return r;
}

// scalar slots: sf[0]=max|x|, sf[1..4]=max|w1,w2,w3,ws|
// si[5]=maxL1, si[6]=maxL2, si[7]=maxAcc3, si[8]=maxAccS
// bnb: inv1[0:384] beta1[384:768] inv2[768:1152] beta2[1152:1536]
//      inv3[1536:1632] beta3[1632:1728] invs[1728:1824] betas[1824:1920]

__global__ __launch_bounds__(1024) void k_init_bn(
    float* sf, float* bnb,
    const float* g1, const float* b1, const float* m1, const float* v1,
    const float* g2, const float* b2, const float* m2, const float* v2,
    const float* g3, const float* b3, const float* m3, const float* v3,
    const float* gs, const float* bs, const float* ms, const float* vs)
{
    int t = threadIdx.x;
    if (t < 32) ((int*)sf)[t] = 0;
    if (t < 384) {
        float inv = __fmul_rn(g1[t], __fdiv_rn(1.0f, sqrtf(__fadd_rn(v1[t], 1e-5f))));
        bnb[t] = inv;
        bnb[384 + t] = __fsub_rn(b1[t], __fmul_rn(m1[t], inv));
    } else if (t < 768) {
        int i = t - 384;
        float inv = __fmul_rn(g2[i], __fdiv_rn(1.0f, sqrtf(__fadd_rn(v2[i], 1e-5f))));
        bnb[768 + i] = inv;
        bnb[1152 + i] = __fsub_rn(b2[i], __fmul_rn(m2[i], inv));
    } else if (t < 864) {
        int i = t - 768;
        float inv = __fmul_rn(g3[i], __fdiv_rn(1.0f, sqrtf(__fadd_rn(v3[i], 1e-5f))));
        bnb[1536 + i] = inv;
        bnb[1632 + i] = __fsub_rn(b3[i], __fmul_rn(m3[i], inv));
    } else if (t < 960) {
        int i = t - 864;
        float inv = __fmul_rn(gs[i], __fdiv_rn(1.0f, sqrtf(__fadd_rn(vs[i], 1e-5f))));
        bnb[1728 + i] = inv;
        bnb[1824 + i] = __fsub_rn(bs[i], __fmul_rn(ms[i], inv));
    }
}

__global__ __launch_bounds__(256) void k_maxes(
    const float* __restrict__ x, const float* __restrict__ w1,
    const float* __restrict__ w2, const float* __restrict__ w3,
    const float* __restrict__ wsc, float* sf)
{
    __shared__ int red[256];
    int tid = threadIdx.x;
    float m = 0.f;
    if (blockIdx.x < 512) {
        const float4* x4 = (const float4*)x;
        const int n4 = (B_ * CIN * HW_) / 4;   // 1605632
        for (int i = blockIdx.x * 256 + tid; i < n4; i += 512 * 256) {
            float4 v = x4[i];
            m = fmaxf(m, fmaxf(fmaxf(fabsf(v.x), fabsf(v.y)),
                               fmaxf(fabsf(v.z), fabsf(v.w))));
        }
        int bm = block_max(__float_as_int(m), red);
        if (tid == 0) atomicMax((int*)&sf[0], bm);
    } else {
        int seg = blockIdx.x - 512;
        const float* p = seg == 0 ? w1 : seg == 1 ? w2 : seg == 2 ? w3 : wsc;
        int n = seg == 0 ? P_ * CIN : seg == 1 ? P_ * 9 : seg == 2 ? CO_ * P_ : CO_ * CIN;
        for (int i = tid; i < n; i += 256) m = fmaxf(m, fabsf(p[i]));
        int bm = block_max(__float_as_int(m), red);
        if (tid == 0) atomicMax((int*)&sf[1 + seg], bm);
    }
}

__global__ __launch_bounds__(256) void k_quantx(
    const float* __restrict__ x, const float* __restrict__ sf, int* __restrict__ xqp)
{
    int flat = blockIdx.x * 256 + threadIdx.x;     // 6272*256 == 1605632 exact
    const int N = B_ * 16 * HW_;
    if (flat >= N) return;
    float rx = 1.0f / pot_scale(sf[0], 7.0f);      // exact pot
    int hw = flat % HW_;
    int c4 = (flat / HW_) & 15;
    int b  = flat / (16 * HW_);
    const float* xp = x + (size_t)(b * 64 + c4 * 4) * HW_ + hw;
    int q[4];
#pragma unroll
    for (int j = 0; j < 4; j++)
        q[j] = iclamp((int)rintf(__fmul_rn(xp[(size_t)j * HW_], rx)), -8, 7);
    xqp[flat] = pack4(q[0], q[1], q[2], q[3]);
}

// weight quant + repack:
//  w1qp: int4[96*16]  : [g][k]  -> 4 output channels 4g..4g+3 (each int = 4 in-ch)
//  w3qp: int4[24*96]  : [coq][k]-> 4 output channels
//  wsqp: int4[24*16]  : [coq][k]-> 4 output channels
__global__ __launch_bounds__(256) void k_quantw(
    const float* __restrict__ w1, const float* __restrict__ w2,
    const float* __restrict__ w3, const float* __restrict__ wsc,
    const float* __restrict__ sf,
    int* __restrict__ w1qp, int8_t* __restrict__ w2q,
    int* __restrict__ w3qp, int* __restrict__ wsqp)
{
    int flat = blockIdx.x * 256 + threadIdx.x;
    if (flat < 6144) {                               // w1: p=flat>>4, c4=flat&15
        float r = 1.0f / pot_scale(sf[1], 7.f);
        int p = flat >> 4, c4 = flat & 15;
        const float* src = w1 + p * 64 + c4 * 4;
        int q[4];
#pragma unroll
        for (int j = 0; j < 4; j++)
            q[j] = iclamp((int)rintf(__fmul_rn(src[j], r)), -8, 7);
        w1qp[((p >> 2) * 16 + c4) * 4 + (p & 3)] = pack4(q[0], q[1], q[2], q[3]);
    } else if (flat < 15360) {                       // w3: co=i/96, c4=i%96
        int i = flat - 6144;
        float r = 1.0f / pot_scale(sf[3], 7.f);
        int co = i / 96, c4 = i % 96;
        const float* src = w3 + co * 384 + c4 * 4;
        int q[4];
#pragma unroll
        for (int j = 0; j < 4; j++)
            q[j] = iclamp((int)rintf(__fmul_rn(src[j], r)), -8, 7);
        w3qp[((co >> 2) * 96 + c4) * 4 + (co & 3)] = pack4(q[0], q[1], q[2], q[3]);
    } else if (flat < 16896) {                       // ws: co=i>>4, c4=i&15
        int i = flat - 15360;
        float r = 1.0f / pot_scale(sf[4], 7.f);
        int co = i >> 4, c4 = i & 15;
        const float* src = wsc + co * 64 + c4 * 4;
        int q[4];
#pragma unroll
        for (int j = 0; j < 4; j++)
            q[j] = iclamp((int)rintf(__fmul_rn(src[j], r)), -8, 7);
        wsqp[((co >> 2) * 16 + c4) * 4 + (co & 3)] = pack4(q[0], q[1], q[2], q[3]);
    } else if (flat < 20352) {                       // w2: [384*9] int8
        int i = flat - 16896;
        float r = 1.0f / pot_scale(sf[2], 7.f);
        w2q[i] = (int8_t)iclamp((int)rintf(__fmul_rn(w2[i], r)), -8, 7);
    }
}

// expand 1x1 (64->384) + BN1 + QuantReLU4 -> channel-packed levels out1p[b][96][hw]
// 4ch x 4w register tile; weights from global (L1-resident 24KB)
__global__ __launch_bounds__(256) void k_conv1(
    const int* __restrict__ xqp, const int4* __restrict__ w1qp,
    const float* __restrict__ sf, const float* __restrict__ bnb,
    unsigned* __restrict__ out1p, int* si)
{
    __shared__ int xs[16 * W_];
    __shared__ int red[256];
    int tid = threadIdx.x;
    int b = blockIdx.x / H_, h = blockIdx.x % H_;
    for (int i = tid; i < 16 * W_; i += 256)
        xs[i] = xqp[((b * 16 + i / W_) * HW_) + h * W_ + (i % W_)];
    float sprod = __fmul_rn(pot_scale(sf[0], 7.f), pot_scale(sf[1], 7.f));
    __syncthreads();
    int lmax = 0;
    for (int qi = tid; qi < 96 * 14; qi += 256) {    // 1344 tiles, 5.25 iters
        int g = qi / 14, w4 = (qi % 14) * 4;
        int acc[4][4];                               // [ch][w]
#pragma unroll
        for (int c = 0; c < 4; c++)
#pragma unroll
            for (int w = 0; w < 4; w++) acc[c][w] = 0;
        const int4* wp = w1qp + g * 16;
#pragma unroll
        for (int k = 0; k < 16; k++) {
            int4 wv = wp[k];
            int4 xv = *(const int4*)&xs[k * W_ + w4];
            acc[0][0] = dot4(xv.x, wv.x, acc[0][0]); acc[0][1] = dot4(xv.y, wv.x, acc[0][1]);
            acc[0][2] = dot4(xv.z, wv.x, acc[0][2]); acc[0][3] = dot4(xv.w, wv.x, acc[0][3]);
            acc[1][0] = dot4(xv.x, wv.y, acc[1][0]); acc[1][1] = dot4(xv.y, wv.y, acc[1][1]);
            acc[1][2] = dot4(xv.z, wv.y, acc[1][2]); acc[1][3] = dot4(xv.w, wv.y, acc[1][3]);
            acc[2][0] = dot4(xv.x, wv.z, acc[2][0]); acc[2][1] = dot4(xv.y, wv.z, acc[2][1]);
            acc[2][2] = dot4(xv.z, wv.z, acc[2][2]); acc[2][3] = dot4(xv.w, wv.z, acc[2][3]);
            acc[3][0] = dot4(xv.x, wv.w, acc[3][0]); acc[3][1] = dot4(xv.y, wv.w, acc[3][1]);
            acc[3][2] = dot4(xv.z, wv.w, acc[3][2]); acc[3][3] = dot4(xv.w, wv.w, acc[3][3]);
        }
        float4 invv = *(const float4*)&bnb[4 * g];
        float4 betv = *(const float4*)&bnb[384 + 4 * g];
        float inva[4] = {invv.x, invv.y, invv.z, invv.w};
        float beta[4] = {betv.x, betv.y, betv.z, betv.w};
        uint4 ov;
        unsigned* op = (unsigned*)&ov;
#pragma unroll
        for (int w = 0; w < 4; w++) {
            unsigned pkd = 0;
#pragma unroll
            for (int c = 0; c < 4; c++) {
                float y = __fadd_rn(__fmul_rn(__fmul_rn((float)acc[c][w], sprod), inva[c]), beta[c]);
                int L = iclamp((int)rintf(__fmul_rn(y, 4.f)), 0, 15);
                lmax = max(lmax, L);
                pkd |= (unsigned)L << (8 * c);
            }
            op[w] = pkd;
        }
        *(uint4*)(out1p + (size_t)(b * 96 + g) * HW_ + h * W_ + w4) = ov;
    }
    int bm = block_max(lmax, red);
    if (tid == 0) atomicMax(&si[5], bm);
}

// depthwise 3x3 + BN2 + QuantReLU4; 4 channels/int packed; LUT requant
__global__ __launch_bounds__(256) void k_conv2(
    const unsigned* __restrict__ out1p, const int8_t* __restrict__ w2q,
    const float* __restrict__ sf, int* si,
    const float* __restrict__ bnb, unsigned* __restrict__ out2p)
{
    __shared__ int plane[58 * 58];
    __shared__ int red[256];
    int tid = threadIdx.x;
    int b = blockIdx.x / 96, g = blockIdx.x % 96;
    float s_a2 = pot_scale(0.25f * (float)si[5], 7.f);
    float r2 = 0.25f / s_a2;                         // exact pot ratio
    float sprod = __fmul_rn(s_a2, pot_scale(sf[2], 7.f));
    unsigned lutlo = build_lut(r2, 0), luthi = build_lut(r2, 8);
    const unsigned* src = out1p + (size_t)(b * 96 + g) * HW_;
    for (int i = tid; i < 58 * 58; i += 256) {
        int r = i / 58, c = i % 58;
        int pv = 0;
        if (r >= 1 && r <= 56 && c >= 1 && c <= 56)
            pv = lutq4(lutlo, luthi, src[(r - 1) * W_ + (c - 1)]);
        plane[i] = pv;
    }
    int wv[4][9];
#pragma unroll
    for (int c = 0; c < 4; c++)
#pragma unroll
        for (int t = 0; t < 9; t++) wv[c][t] = (int)w2q[(4 * g + c) * 9 + t];
    float4 invv = *(const float4*)&bnb[768 + 4 * g];
    float4 betv = *(const float4*)&bnb[1152 + 4 * g];
    float inva[4] = {invv.x, invv.y, invv.z, invv.w};
    float beta[4] = {betv.x, betv.y, betv.z, betv.w};
    __syncthreads();
    int lmax = 0;
    unsigned* dst = out2p + (size_t)(b * 96 + g) * HW_;
    for (int i = tid; i < HW_; i += 256) {
        int oh = i / W_, ow = i % W_;
        int acc[4] = {0, 0, 0, 0};
#pragma unroll
        for (int j = 0; j < 3; j++) {
#pragma unroll
            for (int l = 0; l < 3; l++) {
                int pv = plane[(oh + j) * 58 + ow + l];
                int t = j * 3 + l;
                acc[0] += (pv & 0xff)         * wv[0][t];
                acc[1] += ((pv >> 8) & 0xff)  * wv[1][t];
                acc[2] += ((pv >> 16) & 0xff) * wv[2][t];
                acc[3] += ((pv >> 24) & 0xff) * wv[3][t];
            }
        }
        unsigned pkd = 0;
#pragma unroll
        for (int c = 0; c < 4; c++) {
            float y = __fadd_rn(__fmul_rn(__fmul_rn((float)acc[c], sprod), inva[c]), beta[c]);
            int L = iclamp((int)rintf(__fmul_rn(y, 4.f)), 0, 15);
            lmax = max(lmax, L);
            pkd |= (unsigned)L << (8 * c);
        }
        dst[i] = pkd;
    }
    int bm = block_max(lmax, red);
    if (tid == 0) atomicMax(&si[6], bm);
}

// project 1x1 (384->96): 4co x 4w tiles, 2 rows per block; weights from global
__global__ __launch_bounds__(256) void k_conv3(
    const unsigned* __restrict__ out2p, const int4* __restrict__ w3qp,
    const float* __restrict__ sf, int* si,
    int16_t* __restrict__ acc3)
{
    __shared__ int a3s[2 * 96 * W_];   // 43KB: [row][c4][w] requantized packed
    __shared__ int red[256];
    int tid = threadIdx.x;
    int b = blockIdx.x / 28, h0 = (blockIdx.x % 28) * 2;
    float s_a3 = pot_scale(0.25f * (float)si[6], 7.f);
    float r3 = 0.25f / s_a3;
    unsigned lutlo = build_lut(r3, 0), luthi = build_lut(r3, 8);
    for (int i = tid; i < 2 * 96 * W_; i += 256) {
        int row = i / (96 * W_), rem = i % (96 * W_), c4 = rem / W_, w = rem % W_;
        unsigned v = out2p[(size_t)(b * 96 + c4) * HW_ + (h0 + row) * W_ + w];
        a3s[i] = lutq4(lutlo, luthi, v);
    }
    __syncthreads();
    int amax = 0;
    for (int qi = tid; qi < 672; qi += 256) {        // row(2) x coq(24) x w4(14)
        int row = qi / 336, rem2 = qi % 336, coq = rem2 / 14, w4 = (rem2 % 14) * 4;
        int acc[4][4];                               // [co][w]
#pragma unroll
        for (int c = 0; c < 4; c++)
#pragma unroll
            for (int w = 0; w < 4; w++) acc[c][w] = 0;
        const int4* wp = w3qp + coq * 96;
        const int* ap = a3s + row * 96 * W_ + w4;
#pragma unroll 8
        for (int k = 0; k < 96; k++) {
            int4 wv = wp[k];
            int4 av = *(const int4*)(ap + k * W_);
            acc[0][0] = dot4(av.x, wv.x, acc[0][0]); acc[0][1] = dot4(av.y, wv.x, acc[0][1]);
            acc[0][2] = dot4(av.z, wv.x, acc[0][2]); acc[0][3] = dot4(av.w, wv.x, acc[0][3]);
            acc[1][0] = dot4(av.x, wv.y, acc[1][0]); acc[1][1] = dot4(av.y, wv.y, acc[1][1]);
            acc[1][2] = dot4(av.z, wv.y, acc[1][2]); acc[1][3] = dot4(av.w, wv.y, acc[1][3]);
            acc[2][0] = dot4(av.x, wv.z, acc[2][0]); acc[2][1] = dot4(av.y, wv.z, acc[2][1]);
            acc[2][2] = dot4(av.z, wv.z, acc[2][2]); acc[2][3] = dot4(av.w, wv.z, acc[2][3]);
            acc[3][0] = dot4(av.x, wv.w, acc[3][0]); acc[3][1] = dot4(av.y, wv.w, acc[3][1]);
            acc[3][2] = dot4(av.z, wv.w, acc[3][2]); acc[3][3] = dot4(av.w, wv.w, acc[3][3]);
        }
#pragma unroll
        for (int c = 0; c < 4; c++) {
            int co = coq * 4 + c;
            amax = max(amax, max(max(abs(acc[c][0]), abs(acc[c][1])),
                                 max(abs(acc[c][2]), abs(acc[c][3]))));
            short4 st = make_short4((short)acc[c][0], (short)acc[c][1],
                                    (short)acc[c][2], (short)acc[c][3]);
            *(short4*)(acc3 + (size_t)(b * CO_ + co) * HW_ + (h0 + row) * W_ + w4) = st;
        }
    }
    int bm = block_max(amax, red);
    if (tid == 0) atomicMax(&si[7], bm);
}

// shortcut 1x1 (64->96): only max|acc| needed
__global__ __launch_bounds__(256) void k_convs(
    const int* __restrict__ xqp, const int4* __restrict__ wsqp, int* si)
{
    __shared__ int xs[16 * W_];
    __shared__ int red[256];
    int tid = threadIdx.x;
    int b = blockIdx.x / H_, h = blockIdx.x % H_;
    for (int i = tid; i < 16 * W_; i += 256)
        xs[i] = xqp[((b * 16 + i / W_) * HW_) + h * W_ + (i % W_)];
    __syncthreads();
    int amax = 0;
    for (int qi = tid; qi < 24 * 14; qi += 256) {    // 336 tiles
        int coq = qi / 14, w4 = (qi % 14) * 4;
        int acc[4][4];
#pragma unroll
        for (int c = 0; c < 4; c++)
#pragma unroll
            for (int w = 0; w < 4; w++) acc[c][w] = 0;
        const int4* wp = wsqp + coq * 16;
#pragma unroll
        for (int k = 0; k < 16; k++) {
            int4 wv = wp[k];
            int4 xv = *(const int4*)&xs[k * W_ + w4];
            acc[0][0] = dot4(xv.x, wv.x, acc[0][0]); acc[0][1] = dot4(xv.y, wv.x, acc[0][1]);
            acc[0][2] = dot4(xv.z, wv.x, acc[0][2]); acc[0][3] = dot4(xv.w, wv.x, acc[0][3]);
            acc[1][0] = dot4(xv.x, wv.y, acc[1][0]); acc[1][1] = dot4(xv.y, wv.y, acc[1][1]);
            acc[1][2] = dot4(xv.z, wv.y, acc[1][2]); acc[1][3] = dot4(xv.w, wv.y, acc[1][3]);
            acc[2][0] = dot4(xv.x, wv.z, acc[2][0]); acc[2][1] = dot4(xv.y, wv.z, acc[2][1]);
            acc[2][2] = dot4(xv.z, wv.z, acc[2][2]); acc[2][3] = dot4(xv.w, wv.z, acc[2][3]);
            acc[3][0] = dot4(xv.x, wv.w, acc[3][0]); acc[3][1] = dot4(xv.y, wv.w, acc[3][1]);
            acc[3][2] = dot4(xv.z, wv.w, acc[3][2]); acc[3][3] = dot4(xv.w, wv.w, acc[3][3]);
        }
#pragma unroll
        for (int c = 0; c < 4; c++)
            amax = max(amax, max(max(abs(acc[c][0]), abs(acc[c][1])),
                                 max(abs(acc[c][2]), abs(acc[c][3]))));
    }
    int bm = block_max(amax, red);
    if (tid == 0) atomicMax(&si[8], bm);
}

// fq8(conv3)+BN3 + fq4(shortcut)+BNs + add + QuantReLU4 -> fp32 out
__global__ __launch_bounds__(256) void k_final(
    const int* __restrict__ xqp, const int4* __restrict__ wsqp,
    const int16_t* __restrict__ acc3, const float* __restrict__ sf,
    const int* __restrict__ si, const float* __restrict__ bnb,
    float* __restrict__ dout)
{
    __shared__ int xs[16 * W_];
    int tid = threadIdx.x;
    int b = blockIdx.x / H_, h = blockIdx.x % H_;
    for (int i = tid; i < 16 * W_; i += 256)
        xs[i] = xqp[((b * 16 + i / W_) * HW_) + h * W_ + (i % W_)];
    float s_a3   = pot_scale(0.25f * (float)si[6], 7.f);
    float sprod3 = __fmul_rn(s_a3, pot_scale(sf[3], 7.f));
    float s_q3   = pot_scale(__fmul_rn(sprod3, (float)si[7]), 127.f);
    float rq3    = sprod3 / s_q3;                    // exact pot ratio
    float sprods = __fmul_rn(pot_scale(sf[0], 7.f), pot_scale(sf[4], 7.f));
    float s_qs   = pot_scale(__fmul_rn(sprods, (float)si[8]), 7.f);
    float rqs    = sprods / s_qs;
    __syncthreads();
    for (int qi = tid; qi < 24 * 14; qi += 256) {    // 336 tiles
        int coq = qi / 14, w4 = (qi % 14) * 4;
        int acc[4][4];
#pragma unroll
        for (int c = 0; c < 4; c++)
#pragma unroll
            for (int w = 0; w < 4; w++) acc[c][w] = 0;
        const int4* wp = wsqp + coq * 16;
#pragma unroll
        for (int k = 0; k < 16; k++) {
            int4 wv = wp[k];
            int4 xv = *(const int4*)&xs[k * W_ + w4];
            acc[0][0] = dot4(xv.x, wv.x, acc[0][0]); acc[0][1] = dot4(xv.y, wv.x, acc[0][1]);
            acc[0][2] = dot4(xv.z, wv.x, acc[0][2]); acc[0][3] = dot4(xv.w, wv.x, acc[0][3]);
            acc[1][0] = dot4(xv.x, wv.y, acc[1][0]); acc[1][1] = dot4(xv.y, wv.y, acc[1][1]);
            acc[1][2] = dot4(xv.z, wv.y, acc[1][2]); acc[1][3] = dot4(xv.w, wv.y, acc[1][3]);
            acc[2][0] = dot4(xv.x, wv.z, acc[2][0]); acc[2][1] = dot4(xv.y, wv.z, acc[2][1]);
            acc[2][2] = dot4(xv.z, wv.z, acc[2][2]); acc[2][3] = dot4(xv.w, wv.z, acc[2][3]);
            acc[3][0] = dot4(xv.x, wv.w, acc[3][0]); acc[3][1] = dot4(xv.y, wv.w, acc[3][1]);
            acc[3][2] = dot4(xv.z, wv.w, acc[3][2]); acc[3][3] = dot4(xv.w, wv.w, acc[3][3]);
        }
        float4 inv3v = *(const float4*)&bnb[1536 + 4 * coq];
        float4 bet3v = *(const float4*)&bnb[1632 + 4 * coq];
        float4 invSv = *(const float4*)&bnb[1728 + 4 * coq];
        float4 betSv = *(const float4*)&bnb[1824 + 4 * coq];
        float inv3a[4] = {inv3v.x, inv3v.y, inv3v.z, inv3v.w};
        float bet3a[4] = {bet3v.x, bet3v.y, bet3v.z, bet3v.w};
        float invSa[4] = {invSv.x, invSv.y, invSv.z, invSv.w};
        float betSa[4] = {betSv.x, betSv.y, betSv.z, betSv.w};
#pragma unroll
        for (int c = 0; c < 4; c++) {
            int co = coq * 4 + c;
            size_t idx = (size_t)(b * CO_ + co) * HW_ + h * W_ + w4;
            short4 c3 = *(const short4*)(acc3 + idx);
            int c3a[4] = {c3.x, c3.y, c3.z, c3.w};
            float4 o4;
            float* o = (float*)&o4;
#pragma unroll
            for (int j = 0; j < 4; j++) {
                int q3 = iclamp((int)rintf(__fmul_rn((float)c3a[j], rq3)), -128, 127);
                float y3 = __fadd_rn(__fmul_rn(__fmul_rn((float)q3, s_q3), inv3a[c]), bet3a[c]);
                int qs = iclamp((int)rintf(__fmul_rn((float)acc[c][j], rqs)), -8, 7);
                float ys = __fadd_rn(__fmul_rn(__fmul_rn((float)qs, s_qs), invSa[c]), betSa[c]);
                float oo = __fadd_rn(y3, ys);
                int L = iclamp((int)rintf(__fmul_rn(oo, 4.f)), 0, 15);
                o[j] = (float)L * 0.25f;
            }
            *(float4*)(dout + idx) = o4;
        }
    }
}

extern "C" void kernel_launch(void* const* d_in, const int* in_sizes, int n_in,
                              void* d_out, int out_size, void* d_ws, size_t ws_size,
                              hipStream_t stream)
{
    const float* x   = (const float*)d_in[0];
    const float* w1  = (const float*)d_in[1];
    const float* g1  = (const float*)d_in[2];
    const float* b1  = (const float*)d_in[3];
    const float* m1  = (const float*)d_in[4];
    const float* v1  = (const float*)d_in[5];
    const float* w2  = (const float*)d_in[6];
    const float* g2  = (const float*)d_in[7];
    const float* b2  = (const float*)d_in[8];
    const float* m2  = (const float*)d_in[9];
    const float* v2  = (const float*)d_in[10];
    const float* w3  = (const float*)d_in[11];
    const float* g3  = (const float*)d_in[12];
    const float* b3  = (const float*)d_in[13];
    const float* m3  = (const float*)d_in[14];
    const float* v3  = (const float*)d_in[15];
    const float* wsc = (const float*)d_in[16];
    const float* gs  = (const float*)d_in[17];
    const float* bs  = (const float*)d_in[18];
    const float* ms  = (const float*)d_in[19];
    const float* vs  = (const float*)d_in[20];

    char* ws = (char*)d_ws;
    float*    sf    = (float*)ws;
    int*      si    = (int*)ws;
    float*    bnb   = (float*)(ws + 256);
    int*      w1qp  = (int*)(ws + 8192);            // 24KB
    int8_t*   w2q   = (int8_t*)(ws + 32768);        // 3.4KB
    int*      w3qp  = (int*)(ws + 36864);           // 36KB
    int*      wsqp  = (int*)(ws + 73728);           // 6KB
    int*      xqp   = (int*)(ws + (1u << 20));      // 6.4MB
    unsigned* out1p = (unsigned*)(ws + (8u << 20)); // 38.5MB
    int16_t*  acc3  = (int16_t*)(ws + (8u << 20));  // aliases out1p (dead after conv2)
    unsigned* out2p = (unsigned*)(ws + (48u << 20));// 38.5MB

    k_init_bn<<<1, 1024, 0, stream>>>(sf, bnb, g1, b1, m1, v1, g2, b2, m2, v2,
                                      g3, b3, m3, v3, gs, bs, ms, vs);
    k_maxes<<<516, 256, 0, stream>>>(x, w1, w2, w3, wsc, sf);
    k_quantx<<<6272, 256, 0, stream>>>(x, sf, xqp);
    k_quantw<<<80, 256, 0, stream>>>(w1, w2, w3, wsc, sf, w1qp, w2q, w3qp, wsqp);
    k_conv1<<<B_ * H_, 256, 0, stream>>>(xqp, (const int4*)w1qp, sf, bnb, out1p, si);
    k_conv2<<<B_ * 96, 256, 0, stream>>>(out1p, w2q, sf, si, bnb, out2p);
    k_conv3<<<B_ * 28, 256, 0, stream>>>(out2p, (const int4*)w3qp, sf, si, acc3);
    k_convs<<<B_ * H_, 256, 0, stream>>>(xqp, (const int4*)wsqp, si);
    k_final<<<B_ * H_, 256, 0, stream>>>(xqp, (const int4*)wsqp, acc3, sf, si, bnb,
                                         (float*)d_out);
}

// Round 4
// 305.071 us; speedup vs baseline: 1.6676x; 1.1152x over previous
//
#include <hip/hip_runtime.h>
#include <stdint.h>

#define B_  32
#define CIN 64
#define H_  56
#define W_  56
#define HW_ 3136
#define P_  384
#define CO_ 96

// exp2(ceil(log2(max(m,1e-8)/n))) computed exactly (handles pot boundary via frexp)
__device__ __forceinline__ float pot_scale(float m, float n) {
    float q = fmaxf(m, 1e-8f) / n;
    int e; float f = frexpf(q, &e);        // q = f*2^e, f in [0.5,1)
    return ldexpf(1.0f, (f == 0.5f) ? (e - 1) : e);
}

// signed 8x int4 dot product (v_dot8_i32_i4)
__device__ __forceinline__ int dot8(int a, int b, int c) {
#if __has_builtin(__builtin_amdgcn_sdot8)
    return __builtin_amdgcn_sdot8(a, b, c, false);
#else
#pragma unroll
    for (int j = 0; j < 8; j++) {
        int av = (a << (28 - 4 * j)) >> 28;
        int bv = (b << (28 - 4 * j)) >> 28;
        c += av * bv;
    }
    return c;
#endif
}

__device__ __forceinline__ int iclamp(int v, int lo, int hi) { return min(max(v, lo), hi); }

// 16-entry level->level LUT (q = min(rint(L*r),7)) packed into two regs, 4b/entry.
// Bit-identical to computing rintf(__fmul_rn((float)L, r)) per element.
__device__ __forceinline__ unsigned build_lut(float r, int lo) {
    unsigned v = 0;
#pragma unroll
    for (int L = 0; L < 8; L++)
        v |= (unsigned)min((int)rintf(__fmul_rn((float)(lo + L), r)), 7) << (4 * L);
    return v;
}
__device__ __forceinline__ int lut1(unsigned lo, unsigned hi, int L) {
    unsigned sel = (L & 8) ? hi : lo;
    return (int)((sel >> ((L & 7) * 4)) & 7u);
}
// 4 level-bytes -> 4 nibbles (bits 0..15)
__device__ __forceinline__ unsigned lutn4(unsigned lo, unsigned hi, unsigned v) {
    return (unsigned)lut1(lo, hi, (int)(v & 0xffu))
         | ((unsigned)lut1(lo, hi, (int)((v >> 8) & 0xffu)) << 4)
         | ((unsigned)lut1(lo, hi, (int)((v >> 16) & 0xffu)) << 8)
         | ((unsigned)lut1(lo, hi, (int)((v >> 24) & 0xffu)) << 12);
}

__device__ __forceinline__ int block_max(int v, int* red) {
    int tid = threadIdx.x;
    red[tid] = v; __syncthreads();
    for (int s = 128; s > 0; s >>= 1) {
        if (tid < s) red[tid] = max(red[tid], red[tid + s]);
        __syncthreads();
    }
    int r = red[0];
    __syncthreads();
    return r;
}

// scalar slots: sf[0]=max|x|, sf[1..4]=max|w1,w2,w3,ws|
// si[5]=maxL1, si[6]=maxL2, si[7]=maxAcc3, si[8]=maxAccS
// bnb: inv1[0:384] beta1[384:768] inv2[768:1152] beta2[1152:1536]
//      inv3[1536:1632] beta3[1632:1728] invs[1728:1824] betas[1824:1920]

__global__ __launch_bounds__(1024) void k_init_bn(
    float* sf, float* bnb,
    const float* g1, const float* b1, const float* m1, const float* v1,
    const float* g2, const float* b2, const float* m2, const float* v2,
    const float* g3, const float* b3, const float* m3, const float* v3,
    const float* gs, const float* bs, const float* ms, const float* vs)
{
    int t = threadIdx.x;
    if (t < 32) ((int*)sf)[t] = 0;
    if (t < 384) {
        float inv = __fmul_rn(g1[t], __fdiv_rn(1.0f, sqrtf(__fadd_rn(v1[t], 1e-5f))));
        bnb[t] = inv;
        bnb[384 + t] = __fsub_rn(b1[t], __fmul_rn(m1[t], inv));
    } else if (t < 768) {
        int i = t - 384;
        float inv = __fmul_rn(g2[i], __fdiv_rn(1.0f, sqrtf(__fadd_rn(v2[i], 1e-5f))));
        bnb[768 + i] = inv;
        bnb[1152 + i] = __fsub_rn(b2[i], __fmul_rn(m2[i], inv));
    } else if (t < 864) {
        int i = t - 768;
        float inv = __fmul_rn(g3[i], __fdiv_rn(1.0f, sqrtf(__fadd_rn(v3[i], 1e-5f))));
        bnb[1536 + i] = inv;
        bnb[1632 + i] = __fsub_rn(b3[i], __fmul_rn(m3[i], inv));
    } else if (t < 960) {
        int i = t - 864;
        float inv = __fmul_rn(gs[i], __fdiv_rn(1.0f, sqrtf(__fadd_rn(vs[i], 1e-5f))));
        bnb[1728 + i] = inv;
        bnb[1824 + i] = __fsub_rn(bs[i], __fmul_rn(ms[i], inv));
    }
}

__global__ __launch_bounds__(256) void k_maxes(
    const float* __restrict__ x, const float* __restrict__ w1,
    const float* __restrict__ w2, const float* __restrict__ w3,
    const float* __restrict__ wsc, float* sf)
{
    __shared__ int red[256];
    int tid = threadIdx.x;
    float m = 0.f;
    if (blockIdx.x < 512) {
        const float4* x4 = (const float4*)x;
        const int n4 = (B_ * CIN * HW_) / 4;   // 1605632
        for (int i = blockIdx.x * 256 + tid; i < n4; i += 512 * 256) {
            float4 v = x4[i];
            m = fmaxf(m, fmaxf(fmaxf(fabsf(v.x), fabsf(v.y)),
                               fmaxf(fabsf(v.z), fabsf(v.w))));
        }
        int bm = block_max(__float_as_int(m), red);
        if (tid == 0) atomicMax((int*)&sf[0], bm);
    } else {
        int seg = blockIdx.x - 512;
        const float* p = seg == 0 ? w1 : seg == 1 ? w2 : seg == 2 ? w3 : wsc;
        int n = seg == 0 ? P_ * CIN : seg == 1 ? P_ * 9 : seg == 2 ? CO_ * P_ : CO_ * CIN;
        for (int i = tid; i < n; i += 256) m = fmaxf(m, fabsf(p[i]));
        int bm = block_max(__float_as_int(m), red);
        if (tid == 0) atomicMax((int*)&sf[1 + seg], bm);
    }
}

// x -> nibble-packed int4: xq4[b][c8=8][hw], nibble j = channel 8*c8+j
__global__ __launch_bounds__(256) void k_quantx(
    const float* __restrict__ x, const float* __restrict__ sf, int* __restrict__ xq4)
{
    int flat = blockIdx.x * 256 + threadIdx.x;     // 3136*256 == 802816 exact
    float rx = 1.0f / pot_scale(sf[0], 7.0f);      // exact pot
    int hw = flat % HW_;
    int c8 = (flat / HW_) & 7;
    int b  = flat / (8 * HW_);
    const float* xp = x + (size_t)(b * 64 + c8 * 8) * HW_ + hw;
    unsigned pk = 0;
#pragma unroll
    for (int j = 0; j < 8; j++) {
        int q = iclamp((int)rintf(__fmul_rn(xp[(size_t)j * HW_], rx)), -8, 7);
        pk |= (unsigned)(q & 0xF) << (4 * j);
    }
    xq4[flat] = (int)pk;
}

// weight quant + nibble repack:
//  w1n: [g=96][k8=8][co=4] dwords (12KB), dword = in-ch 8k8..8k8+7 of out-ch 4g+co
//  w3n: [coq=24][k8=48][co=4] dwords (18KB)
//  wsn: [coq=24][k8=8][co=4] dwords (3KB)
//  w2q: int8[384*9]
__global__ __launch_bounds__(256) void k_quantw(
    const float* __restrict__ w1, const float* __restrict__ w2,
    const float* __restrict__ w3, const float* __restrict__ wsc,
    const float* __restrict__ sf,
    int* __restrict__ w1n, int8_t* __restrict__ w2q,
    int* __restrict__ w3n, int* __restrict__ wsn)
{
    int flat = blockIdx.x * 256 + threadIdx.x;
    if (flat < 3072) {                               // w1n
        int d = flat, co = d & 3, k8 = (d >> 2) & 7, g = d >> 5;
        float r = 1.0f / pot_scale(sf[1], 7.f);
        const float* src = w1 + (4 * g + co) * 64 + 8 * k8;
        unsigned pk = 0;
#pragma unroll
        for (int j = 0; j < 8; j++) {
            int q = iclamp((int)rintf(__fmul_rn(src[j], r)), -8, 7);
            pk |= (unsigned)(q & 0xF) << (4 * j);
        }
        w1n[d] = (int)pk;
    } else if (flat < 7680) {                        // w3n
        int d = flat - 3072, co = d & 3, k8 = (d >> 2) % 48, coq = d / 192;
        float r = 1.0f / pot_scale(sf[3], 7.f);
        const float* src = w3 + (4 * coq + co) * 384 + 8 * k8;
        unsigned pk = 0;
#pragma unroll
        for (int j = 0; j < 8; j++) {
            int q = iclamp((int)rintf(__fmul_rn(src[j], r)), -8, 7);
            pk |= (unsigned)(q & 0xF) << (4 * j);
        }
        w3n[d] = (int)pk;
    } else if (flat < 8448) {                        // wsn
        int d = flat - 7680, co = d & 3, k8 = (d >> 2) & 7, coq = d >> 5;
        float r = 1.0f / pot_scale(sf[4], 7.f);
        const float* src = wsc + (4 * coq + co) * 64 + 8 * k8;
        unsigned pk = 0;
#pragma unroll
        for (int j = 0; j < 8; j++) {
            int q = iclamp((int)rintf(__fmul_rn(src[j], r)), -8, 7);
            pk |= (unsigned)(q & 0xF) << (4 * j);
        }
        wsn[d] = (int)pk;
    } else if (flat < 11904) {                       // w2: [384*9] int8
        int i = flat - 8448;
        float r = 1.0f / pot_scale(sf[2], 7.f);
        w2q[i] = (int8_t)iclamp((int)rintf(__fmul_rn(w2[i], r)), -8, 7);
    }
}

// expand 1x1 (64->384) + BN1 + QuantReLU4 -> byte-packed levels out1p[b][96][hw]
// + fused shortcut-conv amax (shares staged x row)
__global__ __launch_bounds__(256) void k_conv1(
    const int* __restrict__ xq4, const int4* __restrict__ w1n,
    const int4* __restrict__ wsn,
    const float* __restrict__ sf, const float* __restrict__ bnb,
    unsigned* __restrict__ out1p, int* si)
{
    __shared__ __align__(16) int xs[8 * W_];
    __shared__ int red[256];
    int tid = threadIdx.x;
    int b = blockIdx.x / H_, h = blockIdx.x % H_;
    for (int i = tid; i < 8 * W_; i += 256)
        xs[i] = xq4[((b * 8 + i / W_) * HW_) + h * W_ + (i % W_)];
    float sprod = __fmul_rn(pot_scale(sf[0], 7.f), pot_scale(sf[1], 7.f));
    __syncthreads();
    int lmax = 0;
    for (int qi = tid; qi < 96 * 14; qi += 256) {    // 1344 tiles
        int g = qi / 14, w4 = (qi % 14) * 4;
        int acc[4][4];                               // [co][w]
#pragma unroll
        for (int c = 0; c < 4; c++)
#pragma unroll
            for (int w = 0; w < 4; w++) acc[c][w] = 0;
        const int4* wp = w1n + g * 8;
#pragma unroll
        for (int k = 0; k < 8; k++) {
            int4 wv = wp[k];
            int4 xv = *(const int4*)&xs[k * W_ + w4];
            acc[0][0] = dot8(xv.x, wv.x, acc[0][0]); acc[0][1] = dot8(xv.y, wv.x, acc[0][1]);
            acc[0][2] = dot8(xv.z, wv.x, acc[0][2]); acc[0][3] = dot8(xv.w, wv.x, acc[0][3]);
            acc[1][0] = dot8(xv.x, wv.y, acc[1][0]); acc[1][1] = dot8(xv.y, wv.y, acc[1][1]);
            acc[1][2] = dot8(xv.z, wv.y, acc[1][2]); acc[1][3] = dot8(xv.w, wv.y, acc[1][3]);
            acc[2][0] = dot8(xv.x, wv.z, acc[2][0]); acc[2][1] = dot8(xv.y, wv.z, acc[2][1]);
            acc[2][2] = dot8(xv.z, wv.z, acc[2][2]); acc[2][3] = dot8(xv.w, wv.z, acc[2][3]);
            acc[3][0] = dot8(xv.x, wv.w, acc[3][0]); acc[3][1] = dot8(xv.y, wv.w, acc[3][1]);
            acc[3][2] = dot8(xv.z, wv.w, acc[3][2]); acc[3][3] = dot8(xv.w, wv.w, acc[3][3]);
        }
        float4 invv = *(const float4*)&bnb[4 * g];
        float4 betv = *(const float4*)&bnb[384 + 4 * g];
        float inva[4] = {invv.x, invv.y, invv.z, invv.w};
        float beta[4] = {betv.x, betv.y, betv.z, betv.w};
        uint4 ov;
        unsigned* op = (unsigned*)&ov;
#pragma unroll
        for (int w = 0; w < 4; w++) {
            unsigned pkd = 0;
#pragma unroll
            for (int c = 0; c < 4; c++) {
                float y = __fadd_rn(__fmul_rn(__fmul_rn((float)acc[c][w], sprod), inva[c]), beta[c]);
                int L = iclamp((int)rintf(__fmul_rn(y, 4.f)), 0, 15);
                lmax = max(lmax, L);
                pkd |= (unsigned)L << (8 * c);
            }
            op[w] = pkd;
        }
        *(uint4*)(out1p + (size_t)(b * 96 + g) * HW_ + h * W_ + w4) = ov;
    }
    int bm = block_max(lmax, red);
    if (tid == 0) atomicMax(&si[5], bm);
    // fused shortcut 1x1 amax (values recomputed in k_final)
    int amax = 0;
    for (int qi = tid; qi < 24 * 14; qi += 256) {    // 336 tiles
        int coq = qi / 14, w4 = (qi % 14) * 4;
        int acc[4][4];
#pragma unroll
        for (int c = 0; c < 4; c++)
#pragma unroll
            for (int w = 0; w < 4; w++) acc[c][w] = 0;
        const int4* wp = wsn + coq * 8;
#pragma unroll
        for (int k = 0; k < 8; k++) {
            int4 wv = wp[k];
            int4 xv = *(const int4*)&xs[k * W_ + w4];
            acc[0][0] = dot8(xv.x, wv.x, acc[0][0]); acc[0][1] = dot8(xv.y, wv.x, acc[0][1]);
            acc[0][2] = dot8(xv.z, wv.x, acc[0][2]); acc[0][3] = dot8(xv.w, wv.x, acc[0][3]);
            acc[1][0] = dot8(xv.x, wv.y, acc[1][0]); acc[1][1] = dot8(xv.y, wv.y, acc[1][1]);
            acc[1][2] = dot8(xv.z, wv.y, acc[1][2]); acc[1][3] = dot8(xv.w, wv.y, acc[1][3]);
            acc[2][0] = dot8(xv.x, wv.z, acc[2][0]); acc[2][1] = dot8(xv.y, wv.z, acc[2][1]);
            acc[2][2] = dot8(xv.z, wv.z, acc[2][2]); acc[2][3] = dot8(xv.w, wv.z, acc[2][3]);
            acc[3][0] = dot8(xv.x, wv.w, acc[3][0]); acc[3][1] = dot8(xv.y, wv.w, acc[3][1]);
            acc[3][2] = dot8(xv.z, wv.w, acc[3][2]); acc[3][3] = dot8(xv.w, wv.w, acc[3][3]);
        }
#pragma unroll
        for (int c = 0; c < 4; c++)
            amax = max(amax, max(max(abs(acc[c][0]), abs(acc[c][1])),
                                 max(abs(acc[c][2]), abs(acc[c][3]))));
    }
    bm = block_max(amax, red);
    if (tid == 0) atomicMax(&si[8], bm);
}

// depthwise 3x3 + BN2 + QuantReLU4; 4 channels/int byte-packed; LUT requant
__global__ __launch_bounds__(256) void k_conv2(
    const unsigned* __restrict__ out1p, const int8_t* __restrict__ w2q,
    const float* __restrict__ sf, int* si,
    const float* __restrict__ bnb, unsigned* __restrict__ out2p)
{
    __shared__ int plane[58 * 58];
    __shared__ int red[256];
    int tid = threadIdx.x;
    int b = blockIdx.x / 96, g = blockIdx.x % 96;
    float s_a2 = pot_scale(0.25f * (float)si[5], 7.f);
    float r2 = 0.25f / s_a2;                         // exact pot ratio
    float sprod = __fmul_rn(s_a2, pot_scale(sf[2], 7.f));
    unsigned lutlo = build_lut(r2, 0), luthi = build_lut(r2, 8);
    const unsigned* src = out1p + (size_t)(b * 96 + g) * HW_;
    for (int i = tid; i < 58 * 58; i += 256) {
        int r = i / 58, c = i % 58;
        int pv = 0;
        if (r >= 1 && r <= 56 && c >= 1 && c <= 56) {
            unsigned v = src[(r - 1) * W_ + (c - 1)];
            pv = lut1(lutlo, luthi, (int)(v & 0xffu))
               | (lut1(lutlo, luthi, (int)((v >> 8) & 0xffu)) << 8)
               | (lut1(lutlo, luthi, (int)((v >> 16) & 0xffu)) << 16)
               | (lut1(lutlo, luthi, (int)((v >> 24) & 0xffu)) << 24);
        }
        plane[i] = pv;
    }
    int wv[4][9];
#pragma unroll
    for (int c = 0; c < 4; c++)
#pragma unroll
        for (int t = 0; t < 9; t++) wv[c][t] = (int)w2q[(4 * g + c) * 9 + t];
    float4 invv = *(const float4*)&bnb[768 + 4 * g];
    float4 betv = *(const float4*)&bnb[1152 + 4 * g];
    float inva[4] = {invv.x, invv.y, invv.z, invv.w};
    float beta[4] = {betv.x, betv.y, betv.z, betv.w};
    __syncthreads();
    int lmax = 0;
    unsigned* dst = out2p + (size_t)(b * 96 + g) * HW_;
    for (int i = tid; i < HW_; i += 256) {
        int oh = i / W_, ow = i % W_;
        int acc[4] = {0, 0, 0, 0};
#pragma unroll
        for (int j = 0; j < 3; j++) {
#pragma unroll
            for (int l = 0; l < 3; l++) {
                int pv = plane[(oh + j) * 58 + ow + l];
                int t = j * 3 + l;
                acc[0] += (pv & 0xff)         * wv[0][t];
                acc[1] += ((pv >> 8) & 0xff)  * wv[1][t];
                acc[2] += ((pv >> 16) & 0xff) * wv[2][t];
                acc[3] += ((pv >> 24) & 0xff) * wv[3][t];
            }
        }
        unsigned pkd = 0;
#pragma unroll
        for (int c = 0; c < 4; c++) {
            float y = __fadd_rn(__fmul_rn(__fmul_rn((float)acc[c], sprod), inva[c]), beta[c]);
            int L = iclamp((int)rintf(__fmul_rn(y, 4.f)), 0, 15);
            lmax = max(lmax, L);
            pkd |= (unsigned)L << (8 * c);
        }
        dst[i] = pkd;
    }
    int bm = block_max(lmax, red);
    if (tid == 0) atomicMax(&si[6], bm);
}

// project 1x1 (384->96): nibble-packed K, dot8; 2 rows/block, int16 acc out
__global__ __launch_bounds__(256) void k_conv3(
    const unsigned* __restrict__ out2p, const int4* __restrict__ w3n,
    const float* __restrict__ sf, int* si,
    int16_t* __restrict__ acc3)
{
    __shared__ __align__(16) int a3s[2 * 48 * W_];   // 21.5KB nibble-packed
    __shared__ int red[256];
    int tid = threadIdx.x;
    int b = blockIdx.x / 28, h0 = (blockIdx.x % 28) * 2;
    float s_a3 = pot_scale(0.25f * (float)si[6], 7.f);
    float r3 = 0.25f / s_a3;
    unsigned lutlo = build_lut(r3, 0), luthi = build_lut(r3, 8);
    for (int i = tid; i < 2 * 48 * W_; i += 256) {   // 5376 = 21*256 exact
        int row = i / (48 * W_), rem = i % (48 * W_), c8 = rem / W_, w = rem % W_;
        size_t base = (size_t)(b * 96 + c8 * 2) * HW_ + (h0 + row) * W_ + w;
        unsigned v0 = out2p[base], v1 = out2p[base + HW_];
        a3s[i] = (int)(lutn4(lutlo, luthi, v0) | (lutn4(lutlo, luthi, v1) << 16));
    }
    __syncthreads();
    int amax = 0;
    for (int qi = tid; qi < 672; qi += 256) {        // row(2) x coq(24) x w4(14)
        int row = qi / 336, rem2 = qi % 336, coq = rem2 / 14, w4 = (rem2 % 14) * 4;
        int acc[4][4];                               // [co][w]
#pragma unroll
        for (int c = 0; c < 4; c++)
#pragma unroll
            for (int w = 0; w < 4; w++) acc[c][w] = 0;
        const int4* wp = w3n + coq * 48;
        const int* ap = a3s + row * 48 * W_ + w4;
#pragma unroll 6
        for (int k = 0; k < 48; k++) {
            int4 wv = wp[k];
            int4 av = *(const int4*)(ap + k * W_);
            acc[0][0] = dot8(av.x, wv.x, acc[0][0]); acc[0][1] = dot8(av.y, wv.x, acc[0][1]);
            acc[0][2] = dot8(av.z, wv.x, acc[0][2]); acc[0][3] = dot8(av.w, wv.x, acc[0][3]);
            acc[1][0] = dot8(av.x, wv.y, acc[1][0]); acc[1][1] = dot8(av.y, wv.y, acc[1][1]);
            acc[1][2] = dot8(av.z, wv.y, acc[1][2]); acc[1][3] = dot8(av.w, wv.y, acc[1][3]);
            acc[2][0] = dot8(av.x, wv.z, acc[2][0]); acc[2][1] = dot8(av.y, wv.z, acc[2][1]);
            acc[2][2] = dot8(av.z, wv.z, acc[2][2]); acc[2][3] = dot8(av.w, wv.z, acc[2][3]);
            acc[3][0] = dot8(av.x, wv.w, acc[3][0]); acc[3][1] = dot8(av.y, wv.w, acc[3][1]);
            acc[3][2] = dot8(av.z, wv.w, acc[3][2]); acc[3][3] = dot8(av.w, wv.w, acc[3][3]);
        }
#pragma unroll
        for (int c = 0; c < 4; c++) {
            int co = coq * 4 + c;
            amax = max(amax, max(max(abs(acc[c][0]), abs(acc[c][1])),
                                 max(abs(acc[c][2]), abs(acc[c][3]))));
            short4 st = make_short4((short)acc[c][0], (short)acc[c][1],
                                    (short)acc[c][2], (short)acc[c][3]);
            *(short4*)(acc3 + (size_t)(b * CO_ + co) * HW_ + (h0 + row) * W_ + w4) = st;
        }
    }
    int bm = block_max(amax, red);
    if (tid == 0) atomicMax(&si[7], bm);
}

// fq8(conv3)+BN3 + fq4(shortcut)+BNs + add + QuantReLU4 -> fp32 out
__global__ __launch_bounds__(256) void k_final(
    const int* __restrict__ xq4, const int4* __restrict__ wsn,
    const int16_t* __restrict__ acc3, const float* __restrict__ sf,
    const int* __restrict__ si, const float* __restrict__ bnb,
    float* __restrict__ dout)
{
    __shared__ __align__(16) int xs[8 * W_];
    int tid = threadIdx.x;
    int b = blockIdx.x / H_, h = blockIdx.x % H_;
    for (int i = tid; i < 8 * W_; i += 256)
        xs[i] = xq4[((b * 8 + i / W_) * HW_) + h * W_ + (i % W_)];
    float s_a3   = pot_scale(0.25f * (float)si[6], 7.f);
    float sprod3 = __fmul_rn(s_a3, pot_scale(sf[3], 7.f));
    float s_q3   = pot_scale(__fmul_rn(sprod3, (float)si[7]), 127.f);
    float rq3    = sprod3 / s_q3;                    // exact pot ratio
    float sprods = __fmul_rn(pot_scale(sf[0], 7.f), pot_scale(sf[4], 7.f));
    float s_qs   = pot_scale(__fmul_rn(sprods, (float)si[8]), 7.f);
    float rqs    = sprods / s_qs;
    __syncthreads();
    for (int qi = tid; qi < 24 * 14; qi += 256) {    // 336 tiles
        int coq = qi / 14, w4 = (qi % 14) * 4;
        int acc[4][4];
#pragma unroll
        for (int c = 0; c < 4; c++)
#pragma unroll
            for (int w = 0; w < 4; w++) acc[c][w] = 0;
        const int4* wp = wsn + coq * 8;
#pragma unroll
        for (int k = 0; k < 8; k++) {
            int4 wv = wp[k];
            int4 xv = *(const int4*)&xs[k * W_ + w4];
            acc[0][0] = dot8(xv.x, wv.x, acc[0][0]); acc[0][1] = dot8(xv.y, wv.x, acc[0][1]);
            acc[0][2] = dot8(xv.z, wv.x, acc[0][2]); acc[0][3] = dot8(xv.w, wv.x, acc[0][3]);
            acc[1][0] = dot8(xv.x, wv.y, acc[1][0]); acc[1][1] = dot8(xv.y, wv.y, acc[1][1]);
            acc[1][2] = dot8(xv.z, wv.y, acc[1][2]); acc[1][3] = dot8(xv.w, wv.y, acc[1][3]);
            acc[2][0] = dot8(xv.x, wv.z, acc[2][0]); acc[2][1] = dot8(xv.y, wv.z, acc[2][1]);
            acc[2][2] = dot8(xv.z, wv.z, acc[2][2]); acc[2][3] = dot8(xv.w, wv.z, acc[2][3]);
            acc[3][0] = dot8(xv.x, wv.w, acc[3][0]); acc[3][1] = dot8(xv.y, wv.w, acc[3][1]);
            acc[3][2] = dot8(xv.z, wv.w, acc[3][2]); acc[3][3] = dot8(xv.w, wv.w, acc[3][3]);
        }
        float4 inv3v = *(const float4*)&bnb[1536 + 4 * coq];
        float4 bet3v = *(const float4*)&bnb[1632 + 4 * coq];
        float4 invSv = *(const float4*)&bnb[1728 + 4 * coq];
        float4 betSv = *(const float4*)&bnb[1824 + 4 * coq];
        float inv3a[4] = {inv3v.x, inv3v.y, inv3v.z, inv3v.w};
        float bet3a[4] = {bet3v.x, bet3v.y, bet3v.z, bet3v.w};
        float invSa[4] = {invSv.x, invSv.y, invSv.z, invSv.w};
        float betSa[4] = {betSv.x, betSv.y, betSv.z, betSv.w};
#pragma unroll
        for (int c = 0; c < 4; c++) {
            int co = coq * 4 + c;
            size_t idx = (size_t)(b * CO_ + co) * HW_ + h * W_ + w4;
            short4 c3 = *(const short4*)(acc3 + idx);
            int c3a[4] = {c3.x, c3.y, c3.z, c3.w};
            float4 o4;
            float* o = (float*)&o4;
#pragma unroll
            for (int j = 0; j < 4; j++) {
                int q3 = iclamp((int)rintf(__fmul_rn((float)c3a[j], rq3)), -128, 127);
                float y3 = __fadd_rn(__fmul_rn(__fmul_rn((float)q3, s_q3), inv3a[c]), bet3a[c]);
                int qs = iclamp((int)rintf(__fmul_rn((float)acc[c][j], rqs)), -8, 7);
                float ys = __fadd_rn(__fmul_rn(__fmul_rn((float)qs, s_qs), invSa[c]), betSa[c]);
                float oo = __fadd_rn(y3, ys);
                int L = iclamp((int)rintf(__fmul_rn(oo, 4.f)), 0, 15);
                o[j] = (float)L * 0.25f;
            }
            *(float4*)(dout + idx) = o4;
        }
    }
}

extern "C" void kernel_launch(void* const* d_in, const int* in_sizes, int n_in,
                              void* d_out, int out_size, void* d_ws, size_t ws_size,
                              hipStream_t stream)
{
    const float* x   = (const float*)d_in[0];
    const float* w1  = (const float*)d_in[1];
    const float* g1  = (const float*)d_in[2];
    const float* b1  = (const float*)d_in[3];
    const float* m1  = (const float*)d_in[4];
    const float* v1  = (const float*)d_in[5];
    const float* w2  = (const float*)d_in[6];
    const float* g2  = (const float*)d_in[7];
    const float* b2  = (const float*)d_in[8];
    const float* m2  = (const float*)d_in[9];
    const float* v2  = (const float*)d_in[10];
    const float* w3  = (const float*)d_in[11];
    const float* g3  = (const float*)d_in[12];
    const float* b3  = (const float*)d_in[13];
    const float* m3  = (const float*)d_in[14];
    const float* v3  = (const float*)d_in[15];
    const float* wsc = (const float*)d_in[16];
    const float* gs  = (const float*)d_in[17];
    const float* bs  = (const float*)d_in[18];
    const float* ms  = (const float*)d_in[19];
    const float* vs  = (const float*)d_in[20];

    char* ws = (char*)d_ws;
    float*    sf    = (float*)ws;
    int*      si    = (int*)ws;
    float*    bnb   = (float*)(ws + 256);
    int*      w1n   = (int*)(ws + 8192);            // 12KB
    int8_t*   w2q   = (int8_t*)(ws + 32768);        // 3.4KB
    int*      w3n   = (int*)(ws + 36864);           // 18KB
    int*      wsn   = (int*)(ws + 73728);           // 3KB
    int*      xq4   = (int*)(ws + (1u << 20));      // 3.2MB
    unsigned* out1p = (unsigned*)(ws + (8u << 20)); // 38.5MB
    int16_t*  acc3  = (int16_t*)(ws + (8u << 20));  // aliases out1p (dead after conv2)
    unsigned* out2p = (unsigned*)(ws + (48u << 20));// 38.5MB

    k_init_bn<<<1, 1024, 0, stream>>>(sf, bnb, g1, b1, m1, v1, g2, b2, m2, v2,
                                      g3, b3, m3, v3, gs, bs, ms, vs);
    k_maxes<<<516, 256, 0, stream>>>(x, w1, w2, w3, wsc, sf);
    k_quantx<<<3136, 256, 0, stream>>>(x, sf, xq4);
    k_quantw<<<47, 256, 0, stream>>>(w1, w2, w3, wsc, sf, w1n, w2q, w3n, wsn);
    k_conv1<<<B_ * H_, 256, 0, stream>>>(xq4, (const int4*)w1n, (const int4*)wsn,
                                         sf, bnb, out1p, si);
    k_conv2<<<B_ * 96, 256, 0, stream>>>(out1p, w2q, sf, si, bnb, out2p);
    k_conv3<<<B_ * 28, 256, 0, stream>>>(out2p, (const int4*)w3n, sf, si, acc3);
    k_final<<<B_ * H_, 256, 0, stream>>>(xq4, (const int4*)wsn, acc3, sf, si, bnb,
                                         (float*)d_out);
}